// Round 3
// baseline (370.054 us; speedup 1.0000x reference)
//
#include <hip/hip_runtime.h>

// Problem constants (fixed by the reference):
//   B=8, HEADS=8, N=3136, D=32, K2=9
constexpr int Bc   = 8;
constexpr int Hh   = 8;
constexpr int Nn   = 3136;
constexpr int Dd   = 32;
constexpr int K2c  = 9;
constexpr int ROWS = Bc * Hh * Nn;          // 200704 flattened (b,h,n) rows
constexpr int BLOCK = 256;
constexpr int WPB   = BLOCK / 64;           // 4 waves per block
constexpr int GRID  = 1792;                 // 7 blocks/CU x 256 CU, all co-resident
constexpr int NWAVE = GRID * WPB;           // 7168 waves
constexpr int RUN   = ROWS / NWAVE;         // 28 consecutive rows per wave
constexpr int ITERS = RUN / 2;              // 14 iterations, 2 rows each
static_assert(NWAVE * RUN == ROWS, "exact cover");
static_assert(Nn % RUN == 0, "run never crosses a head boundary");
constexpr int VROW = Dd * K2c;              // 288 floats per v row

// Wave-autonomous streaming kernel: ZERO __syncthreads in the steady state.
// Each wave: half = lane>>5 selects one of 2 rows, d = lane&31 the output dim.
// attn[row][k] = (sum_d q[row][d]*T[d][k]) + attn_local + bias, computed by a
// 32-lane shfl_xor butterfly (all lanes of a half end up with the sum), then
// immediately consumed: acc += attn_k * v[row][d][k]. Register double-buffer
// prefetches iteration i+1's v/q/al+bias while computing iteration i, so HBM
// always has loads in flight (no vmcnt(0) drains anywhere in the loop).
__global__ __launch_bounds__(BLOCK, 7)
void swattn_av_kernel(const float* __restrict__ q,          // [B,H,N,D]
                      const float* __restrict__ attn_local, // [B,H,N,K2]
                      const float* __restrict__ v,          // [B,H,N,D,K2]
                      const float* __restrict__ tok,        // [H,D,K2]
                      const float* __restrict__ bias,       // [H,N,K2]
                      float* __restrict__ out) {            // [B,H,N,D]
    __shared__ float T_lds[VROW];                 // this block's head (h uniform: see below)

    const int tid  = threadIdx.x;
    const int lane = tid & 63;
    const int wid  = tid >> 6;
    const int W    = blockIdx.x * WPB + wid;      // global wave id
    const int runBase = W * RUN;                  // first row of this wave's 28-row run
    // h uniform per block: runs are 28 rows, 3136 % 28 == 0 and 25088 % 28 == 0,
    // and a block's 4 waves never straddle a head boundary (112-wave windows).
    const int h    = (runBase / Nn) & (Hh - 1);
    const int half = lane >> 5;                   // which of the iteration's 2 rows
    const int d    = lane & 31;                   // output dim
    const bool l9  = (d < K2c);                   // lanes holding attn_local+bias
    const int brem = runBase % (Hh * Nn) + half;  // (h*N + n) for iter 0; +2 per iter

    // One-time T staging (72 float4), the only barrier in the kernel.
    if (tid < VROW / 4)
        reinterpret_cast<float4*>(T_lds)[tid] =
            reinterpret_cast<const float4*>(tok + h * VROW)[tid];
    __syncthreads();

    float vA[K2c], vB[K2c];
    float qA = 0.f, qB = 0.f, aA = 0.f, aB = 0.f;

    auto prefetch = [&](int i, float (&vr)[K2c], float& qr, float& ar) {
        const int r0  = runBase + 2 * i;
        const int row = r0 + half;
        const float* __restrict__ vp = v + (size_t)row * VROW + d * K2c;
        #pragma unroll
        for (int k = 0; k < K2c; ++k) vr[k] = vp[k];   // 36 B/lane, L1-merged
        qr = q[r0 * Dd + lane];                        // 256 B contiguous per wave
        if (l9)                                        // 72 B contiguous per wave
            ar = attn_local[row * K2c + d] + bias[(brem + 2 * i) * K2c + d];
    };

    auto compute = [&](int i, float (&vr)[K2c], float qr, float ar) {
        float acc = 0.f;
        #pragma unroll
        for (int k = 0; k < K2c; ++k) {
            // partial product for this lane's d; butterfly-sum over the 32 d-lanes
            float p = qr * T_lds[d * K2c + k];         // 9d+k mod 32: all banks, bcast halves
            p += __shfl_xor(p, 1, 32);
            p += __shfl_xor(p, 2, 32);
            p += __shfl_xor(p, 4, 32);
            p += __shfl_xor(p, 8, 32);
            p += __shfl_xor(p, 16, 32);
            // add attn_local+bias (held in lane k of each half), consume immediately
            acc += (p + __shfl(ar, k, 32)) * vr[k];
        }
        out[(runBase + 2 * i) * Dd + lane] = acc;      // 256 B contiguous per wave
    };

    prefetch(0, vA, qA, aA);
    #pragma unroll
    for (int i = 0; i < ITERS; i += 2) {
        prefetch(i + 1, vB, qB, aB);                   // in flight during compute(i)
        compute(i, vA, qA, aA);
        if (i + 2 < ITERS) prefetch(i + 2, vA, qA, aA);
        compute(i + 1, vB, qB, aB);
    }
}

extern "C" void kernel_launch(void* const* d_in, const int* in_sizes, int n_in,
                              void* d_out, int out_size, void* d_ws, size_t ws_size,
                              hipStream_t stream) {
    const float* q          = (const float*)d_in[0];   // q_norm          [B,H,N,D]
    const float* attn_local = (const float*)d_in[1];   // attn_local      [B,H,N,K2]
    const float* v          = (const float*)d_in[2];   // v_local         [B,H,N,D,K2]
    const float* tok        = (const float*)d_in[3];   // learnable_tokens[H,D,K2]
    const float* bias       = (const float*)d_in[4];   // learnable_bias  [H,N,K2]
    // d_in[5..7] = window_size, H, W scalars (unused; K2=9 baked in)
    float* out = (float*)d_out;

    swattn_av_kernel<<<GRID, BLOCK, 0, stream>>>(q, attn_local, v, tok, bias, out);
}

// Round 4
// 348.076 us; speedup vs baseline: 1.0631x; 1.0631x over previous
//
#include <hip/hip_runtime.h>

// Problem constants (fixed by the reference):
//   B=8, HEADS=8, N=3136, D=32, K2=9
constexpr int Hh   = 8;
constexpr int Nn   = 3136;
constexpr int Dd   = 32;
constexpr int K2c  = 9;
constexpr int ROWS = 8 * Hh * Nn;           // 200704 flattened (b,h,n) rows
constexpr int RPB  = 32;                    // rows per block (3136 % 32 == 0)
constexpr int BLOCK = 256;
constexpr int PAIRS = RPB * K2c;            // 288 (row,k) attn pairs per block
constexpr int VROW  = Dd * K2c;             // 288 floats per v row
constexpr int GRID  = ROWS / RPB;           // 6272, exact

__global__ __launch_bounds__(BLOCK, 6)
void swattn_av_kernel(const float* __restrict__ q,          // [B,H,N,D]
                      const float* __restrict__ attn_local, // [B,H,N,K2]
                      const float* __restrict__ v,          // [B,H,N,D,K2]
                      const float* __restrict__ tok,        // [H,D,K2]
                      const float* __restrict__ bias,       // [H,N,K2]
                      float* __restrict__ out) {            // [B,H,N,D]
    __shared__ float T_lds[VROW];               // 288: this block's head tokens
    __shared__ float q_lds[RPB][Dd + 1];        // 32x33: pad -> Phase-A reads conflict-free
    __shared__ float attn_lds[PAIRS];           // 288 attn weights

    const int tid  = threadIdx.x;
    const int base = blockIdx.x * RPB;          // first row; never crosses a head (3136%32==0)
    const int h    = (base / Nn) & (Hh - 1);    // uniform per block
    const int brem = base % (Hh * Nn);          // (h*N + n0) for bias indexing

    // ---- Phase 0: staging, all loads coalesced ----
    // q: 32 rows x 32 d = 256 float4, one per thread
    {
        const float4 qv = reinterpret_cast<const float4*>(q + (size_t)base * Dd)[tid];
        const int r = tid >> 3, c = (tid & 7) * 4;   // scalar stores (pad breaks f4 align)
        q_lds[r][c + 0] = qv.x;
        q_lds[r][c + 1] = qv.y;
        q_lds[r][c + 2] = qv.z;
        q_lds[r][c + 3] = qv.w;
    }
    // tok: 72 float4
    if (tid < VROW / 4)
        reinterpret_cast<float4*>(T_lds)[tid] =
            reinterpret_cast<const float4*>(tok + h * VROW)[tid];
    // attn_local + bias for pair p = tid (and p = 256+tid for tid<32): coalesced dwords
    const float a0 = attn_local[(size_t)base * K2c + tid] + bias[(size_t)brem * K2c + tid];
    float a1 = 0.f;
    if (tid < PAIRS - BLOCK)
        a1 = attn_local[(size_t)base * K2c + BLOCK + tid]
           + bias[(size_t)brem * K2c + BLOCK + tid];
    __syncthreads();

    // ---- Issue this thread's v slice NOW: 9 aligned float4 (144 B), flies under Phase A ----
    const int row = tid >> 3;                   // 0..31
    const int d0  = (tid & 7) * 4;              // 0,4,..,28
    float4 vf[9];
    {
        const float4* __restrict__ vp = reinterpret_cast<const float4*>(
            v + (size_t)(base + row) * VROW + d0 * K2c);   // d0*36B: 16B-aligned
        #pragma unroll
        for (int j = 0; j < 9; ++j) vf[j] = vp[j];
    }

    // ---- Phase A: 256 threads compute 288 attn pairs (full-width) ----
    {
        const int p  = tid, ar = p / K2c, ak = p - ar * K2c;
        float s = 0.f;
        #pragma unroll
        for (int dd = 0; dd < Dd; ++dd)
            s += q_lds[ar][dd] * T_lds[dd * K2c + ak];   // banks (ar+dd)%32: conflict-free
        attn_lds[p] = s + a0;
    }
    if (tid < PAIRS - BLOCK) {
        const int p  = BLOCK + tid, ar = p / K2c, ak = p - ar * K2c;
        float s = 0.f;
        #pragma unroll
        for (int dd = 0; dd < Dd; ++dd)
            s += q_lds[ar][dd] * T_lds[dd * K2c + ak];
        attn_lds[p] = s + a1;
    }
    __syncthreads();

    // ---- Phase B: 4 outputs/thread from registers + broadcast LDS attn ----
    {
        float af[K2c];
        #pragma unroll
        for (int k = 0; k < K2c; ++k)
            af[k] = attn_lds[row * K2c + k];    // 8 lanes/row -> broadcast
        float acc[4] = {0.f, 0.f, 0.f, 0.f};
        #pragma unroll
        for (int j = 0; j < 9; ++j) {           // dword idx = 4j+e -> d=(idx)/9, k=(idx)%9
            const float e0 = vf[j].x, e1 = vf[j].y, e2 = vf[j].z, e3 = vf[j].w;
            acc[(4 * j + 0) / K2c] += af[(4 * j + 0) % K2c] * e0;
            acc[(4 * j + 1) / K2c] += af[(4 * j + 1) % K2c] * e1;
            acc[(4 * j + 2) / K2c] += af[(4 * j + 2) % K2c] * e2;
            acc[(4 * j + 3) / K2c] += af[(4 * j + 3) % K2c] * e3;
        }
        float4 o; o.x = acc[0]; o.y = acc[1]; o.z = acc[2]; o.w = acc[3];
        // wave stores 64 x 16B = 1KB contiguous
        reinterpret_cast<float4*>(out + (size_t)(base + row) * Dd)[tid & 7] = o;
    }
}

extern "C" void kernel_launch(void* const* d_in, const int* in_sizes, int n_in,
                              void* d_out, int out_size, void* d_ws, size_t ws_size,
                              hipStream_t stream) {
    const float* q          = (const float*)d_in[0];   // q_norm          [B,H,N,D]
    const float* attn_local = (const float*)d_in[1];   // attn_local      [B,H,N,K2]
    const float* v          = (const float*)d_in[2];   // v_local         [B,H,N,D,K2]
    const float* tok        = (const float*)d_in[3];   // learnable_tokens[H,D,K2]
    const float* bias       = (const float*)d_in[4];   // learnable_bias  [H,N,K2]
    // d_in[5..7] = window_size, H, W scalars (unused; K2=9 baked in)
    float* out = (float*)d_out;

    swattn_av_kernel<<<GRID, BLOCK, 0, stream>>>(q, attn_local, v, tok, bias, out);
}